// Round 1
// baseline (9671.326 us; speedup 1.0000x reference)
//
#include <hip/hip_runtime.h>

#define DEVINL __device__ __forceinline__

// Problem constants
constexpr int kB = 4, kT = 256, kH = 256, kA = 256, kV = 32000;
constexpr int NBLK = 64;   // persistent blocks in coop kernel (1 per CU, 64 << 256 CUs)
constexpr int NTHR = 256;
constexpr int WSL = 4;     // slice width = 256 / NBLK

// ---------------- fast math helpers (hardware transcendentals via asm) -------
DEVINL float fexp2(float x) { float y; asm("v_exp_f32 %0, %1" : "=v"(y) : "v"(x)); return y; }
DEVINL float frcp(float x)  { float y; asm("v_rcp_f32 %0, %1" : "=v"(y) : "v"(x)); return y; }
DEVINL float f_exp(float x) { return fexp2(x * 1.44269504f); }
DEVINL float f_tanh(float x) {
  float t = fexp2(x * 2.88539008f);           // e^{2x}
  return 1.f - 2.f * frcp(t + 1.f);
}
DEVINL float f_sig(float x) { return frcp(1.f + fexp2(-x * 1.44269504f)); }

DEVINL float bfu2f(unsigned short u) {
  union { unsigned int i; float f; } c; c.i = ((unsigned int)u) << 16; return c.f;
}
DEVINL unsigned short f2bfu(float f) {
  union { float f; unsigned int i; } c; c.f = f;
  unsigned int r = c.i + 0x7fffu + ((c.i >> 16) & 1u);   // RNE
  return (unsigned short)(r >> 16);
}

// dot of f32 LDS vector (len 256) with bf16 LDS weight column (len 256)
DEVINL float dot_bf(const float* x, const unsigned short* w) {
  float acc = 0.f;
  const float4*  x4 = (const float4*)x;
  const ushort4* w4 = (const ushort4*)w;
#pragma unroll 8
  for (int i = 0; i < 64; ++i) {
    float4 xv = x4[i]; ushort4 wv = w4[i];
    acc += xv.x * bfu2f(wv.x);
    acc += xv.y * bfu2f(wv.y);
    acc += xv.z * bfu2f(wv.z);
    acc += xv.w * bfu2f(wv.w);
  }
  return acc;
}

// ---------------- grid barrier (all NBLK blocks co-resident) -----------------
DEVINL void gbar(int* bar) {
  __syncthreads();            // drains each wave's vmem stores before release
  if (threadIdx.x == 0) {
    int* cnt = bar;
    int* gen = bar + 32;
    int g = __hip_atomic_load(gen, __ATOMIC_RELAXED, __HIP_MEMORY_SCOPE_AGENT);
    int prev = __hip_atomic_fetch_add(cnt, 1, __ATOMIC_ACQ_REL, __HIP_MEMORY_SCOPE_AGENT);
    if (prev == NBLK - 1) {
      __hip_atomic_store(cnt, 0, __ATOMIC_RELAXED, __HIP_MEMORY_SCOPE_AGENT);
      __hip_atomic_store(gen, g + 1, __ATOMIC_RELEASE, __HIP_MEMORY_SCOPE_AGENT);
    } else {
      int it = 0;
      while (__hip_atomic_load(gen, __ATOMIC_RELAXED, __HIP_MEMORY_SCOPE_AGENT) == g) {
        __builtin_amdgcn_s_sleep(2);
        if (++it > (1 << 27)) break;   // safety bailout (fail loud, not hang)
      }
      (void)__hip_atomic_load(gen, __ATOMIC_ACQUIRE, __HIP_MEMORY_SCOPE_AGENT);
    }
  }
  __syncthreads();
  __builtin_amdgcn_fence(__ATOMIC_ACQUIRE, "agent");  // invalidate L1/L2 so all threads see fresh data
}

// ---------------- small kernels ----------------------------------------------
__global__ void init_kernel(int* bar) { if (threadIdx.x < 64) bar[threadIdx.x] = 0; }

__global__ void embed_kernel(const int* __restrict__ ids, const int* __restrict__ cids,
                             const float* __restrict__ emb, const float* __restrict__ cat_emb,
                             float* __restrict__ li0_all, float* __restrict__ ce_all,
                             float* __restrict__ cat1_all) {
  int bt = blockIdx.x, e = threadIdx.x;
  int id = ids[bt], cid = cids[bt];
  float we = emb[id * kH + e];
  float ce = cat_emb[cid * kH + e];
  li0_all[bt * 512 + e]       = fmaxf(we + ce, 0.f);
  li0_all[bt * 512 + 256 + e] = fmaxf(ce + ce, 0.f);
  ce_all[bt * 256 + e] = ce;
  cat1_all[bt * 512 + 256 + e] = ce;   // upper half of [nh1, ce] concat
}

// ---------------- generic f32 GEMM: C = act(A[M,K] @ W[K,N] + bias) ----------
// BM=BN=64, BK=16, 256 threads, 4x4 per thread. M % 64 == 0 assumed, K % 4 == 0.
template <int ACT>
__global__ __launch_bounds__(256) void gemm_f32(const float* __restrict__ A,
                                                const float* __restrict__ Wm,
                                                const float* __restrict__ bias,
                                                float* __restrict__ C,
                                                int M, int N, int K) {
  __shared__ __align__(16) float As[16][68];
  __shared__ __align__(16) float Bs[16][68];
  int tid = threadIdx.x;
  int tx = tid & 15, ty = tid >> 4;
  int row0 = blockIdx.y * 64, col0 = blockIdx.x * 64;
  int ar = tid >> 2;               // 0..63
  int ak = (tid & 3) * 4;          // 0,4,8,12
  int br = tid >> 4;               // 0..15
  int bc = (tid & 15) * 4;         // 0..60
  float acc[4][4] = {};
  for (int k0 = 0; k0 < K; k0 += 16) {
    float4 av = {0.f, 0.f, 0.f, 0.f};
    if (k0 + ak < K) av = *(const float4*)(A + (size_t)(row0 + ar) * K + k0 + ak);
    As[ak + 0][ar] = av.x; As[ak + 1][ar] = av.y; As[ak + 2][ar] = av.z; As[ak + 3][ar] = av.w;
    float4 bv = {0.f, 0.f, 0.f, 0.f};
    int wrow = k0 + br;
    if (wrow < K) {
      if (col0 + bc + 3 < N) bv = *(const float4*)(Wm + (size_t)wrow * N + col0 + bc);
      else {
        float t[4] = {0.f, 0.f, 0.f, 0.f};
        for (int u = 0; u < 4; ++u) if (col0 + bc + u < N) t[u] = Wm[(size_t)wrow * N + col0 + bc + u];
        bv.x = t[0]; bv.y = t[1]; bv.z = t[2]; bv.w = t[3];
      }
    }
    *(float4*)&Bs[br][bc] = bv;
    __syncthreads();
#pragma unroll
    for (int kk = 0; kk < 16; ++kk) {
      float4 a4 = *(const float4*)&As[kk][ty * 4];
      float4 b4 = *(const float4*)&Bs[kk][tx * 4];
      acc[0][0] += a4.x * b4.x; acc[0][1] += a4.x * b4.y; acc[0][2] += a4.x * b4.z; acc[0][3] += a4.x * b4.w;
      acc[1][0] += a4.y * b4.x; acc[1][1] += a4.y * b4.y; acc[1][2] += a4.y * b4.z; acc[1][3] += a4.y * b4.w;
      acc[2][0] += a4.z * b4.x; acc[2][1] += a4.z * b4.y; acc[2][2] += a4.z * b4.z; acc[2][3] += a4.z * b4.w;
      acc[3][0] += a4.w * b4.x; acc[3][1] += a4.w * b4.y; acc[3][2] += a4.w * b4.z; acc[3][3] += a4.w * b4.w;
    }
    __syncthreads();
  }
#pragma unroll
  for (int i = 0; i < 4; ++i) {
    int r = row0 + ty * 4 + i;
#pragma unroll
    for (int j = 0; j < 4; ++j) {
      int c = col0 + tx * 4 + j;
      if (c < N) {
        float v = acc[i][j] + bias[c];
        if (ACT == 1) v = f_tanh(v);
        C[(size_t)r * N + c] = v;
      }
    }
  }
}

// ---------------- persistent cooperative recurrence kernel -------------------
// 64 blocks x 256 threads. Block i owns column-slice [4i, 4i+4) of A/H dims and
// the matching 3 gate-columns of the 768-wide gate dims. 3 grid barriers per
// super-step; layers pipelined (L0 at step k+1, L1 at step k).
__global__ __launch_bounds__(NTHR, 1) void coop_kernel(
    const float* __restrict__ gi0_all, const float* __restrict__ xw0_all,
    const float* __restrict__ ce_all,
    float* __restrict__ nh0_all, float* __restrict__ nh1_all,
    float* __restrict__ tWh0_g, float* __restrict__ tWh1_g,
    float* __restrict__ hw0_g, float* __restrict__ hw1_g, float* __restrict__ xw1_g,
    float* __restrict__ s0_g, float* __restrict__ s1_g,
    float* __restrict__ cat1_all, float* __restrict__ out_tail, int* __restrict__ bar,
    const float* __restrict__ Whh0, const float* __restrict__ bhh0,
    const float* __restrict__ Wh0, const float* __restrict__ bh0,
    const float* __restrict__ Wth0, const float* __restrict__ bth0,
    const float* __restrict__ v0, const float* __restrict__ bv0,
    const float* __restrict__ Wih1, const float* __restrict__ bih1,
    const float* __restrict__ Whh1, const float* __restrict__ bhh1,
    const float* __restrict__ Wh1, const float* __restrict__ bh1,
    const float* __restrict__ Wx1, const float* __restrict__ bx1,
    const float* __restrict__ Wth1, const float* __restrict__ bth1,
    const float* __restrict__ v1, const float* __restrict__ bv1) {
  // ---- persistent LDS state (~151 KB) ----
  __shared__ __align__(16) unsigned short tWhh0_s[kT][12][4];   // nh@Whh history (bf16)
  __shared__ __align__(16) unsigned short tWhh1_s[kT][12][4];
  __shared__ __align__(16) float tape0_s[kT][17];               // nh history, my 4 h-cols [j][c*4+b]
  __shared__ __align__(16) float tape1_s[kT][17];
  __shared__ __align__(16) unsigned short tWh0_s[WSL][4][272];  // my 4 tape rows of tape@Wh (bf16)
  __shared__ __align__(16) unsigned short tWh1_s[WSL][4][272];
  // weight column-slices (bf16)
  __shared__ __align__(16) unsigned short Wh0c[WSL][264], Wth0c[WSL][264];
  __shared__ __align__(16) unsigned short Wh1c[WSL][264], Wth1c[WSL][264], Wx1c[WSL][264];
  __shared__ __align__(16) unsigned short Whh0c[12][264], Whh1c[12][264], Wih1c[12][264];
  __shared__ __align__(16) float v0s[kA], v1s[kA];
  __shared__ float bh0s[4], bth0s[4], bh1s[4], bth1s[4], bx1s[4];
  __shared__ float bhh0s[12], bhh1s[12], bih1s[12];
  __shared__ float bv0s, bv1s;
  // scratch
  __shared__ __align__(16) float nh0_s[4][260], nh1_s[4][260], li1_s[4][260];
  __shared__ __align__(16) float xps_s[4][260];
  __shared__ __align__(16) float s_s[4][260];
  __shared__ float gh_s[4][12], agg_s[4][4], gi1_s[4][12];

  int bid = blockIdx.x, tid = threadIdx.x;
  int c0 = bid * WSL;

  // ---- load weight slices ----
  for (int idx = tid; idx < WSL * kH; idx += NTHR) {
    int ac = idx >> 8, h = idx & 255, c = c0 + ac;
    Wh0c[ac][h]  = f2bfu(Wh0[h * kA + c]);
    Wth0c[ac][h] = f2bfu(Wth0[h * kA + c]);
    Wh1c[ac][h]  = f2bfu(Wh1[h * kA + c]);
    Wth1c[ac][h] = f2bfu(Wth1[h * kA + c]);
    Wx1c[ac][h]  = f2bfu(Wx1[h * kA + c]);
  }
  for (int idx = tid; idx < 12 * kH; idx += NTHR) {
    int cc = idx >> 8, h = idx & 255;
    int n = (cc >> 2) * kH + c0 + (cc & 3);
    Whh0c[cc][h] = f2bfu(Whh0[h * 768 + n]);
    Whh1c[cc][h] = f2bfu(Whh1[h * 768 + n]);
    Wih1c[cc][h] = f2bfu(Wih1[h * 768 + n]);
  }
  for (int a = tid; a < kA; a += NTHR) { v0s[a] = v0[a]; v1s[a] = v1[a]; }
  if (tid < 4) {
    int c = c0 + tid;
    bh0s[tid] = bh0[c]; bth0s[tid] = bth0[c];
    bh1s[tid] = bh1[c]; bth1s[tid] = bth1[c]; bx1s[tid] = bx1[c];
  }
  if (tid < 12) {
    int n = (tid >> 2) * kH + c0 + (tid & 3);
    bhh0s[tid] = bhh0[n]; bhh1s[tid] = bhh1[n]; bih1s[tid] = bih1[n];
  }
  if (tid == 0) { bv0s = bv0[0]; bv1s = bv1[0]; }
  __syncthreads();

  // ---- prologue: nh0(0) (t=0: agg=h=0, gh=bhh) ----
  if (tid < 16) {
    int b = tid & 3, c = tid >> 2, hcol = c0 + c;
    const float* gi = gi0_all + (size_t)(b * kT + 0) * 768;
    float r = f_sig(gi[hcol] + bhh0s[c]);
    float u = f_sig(gi[256 + hcol] + bhh0s[4 + c]);
    float n = f_tanh(gi[512 + hcol] + r * bhh0s[8 + c]);
    float val = (1.f - u) * n;
    nh0_all[(size_t)(b * kT + 0) * kH + hcol] = val;
    tape0_s[0][c * 4 + b] = val;
  }

  for (int k = 0; k < kT; ++k) {
    gbar(bar);   // publishes nh0(k), nh1(k-1)

    // ================= phase X: incremental products =================
    for (int idx = tid; idx < kB * kH; idx += NTHR) {
      int b = idx >> 8, h = idx & 255;
      float n0 = nh0_all[(size_t)(b * kT + k) * kH + h];
      nh0_s[b][h] = n0;
      float ce = ce_all[(size_t)(b * kT + k) * kH + h];
      li1_s[b][h] = fmaxf(n0 + ce, 0.f);
      if (k > 0) nh1_s[b][h] = nh1_all[(size_t)(b * kT + k - 1) * kH + h];
    }
    __syncthreads();
    {
      int slot = tid;
      if (slot < 80) {                 // layer0 (skip at k==kT-1)
        if (k < kT - 1) {
          if (slot < 16) {             // tapeWh0 row k
            int b = slot & 3, ac = slot >> 2;
            float acc = dot_bf(nh0_s[b], Wh0c[ac]);
            tWh0_g[(size_t)(b * kT + k) * kA + c0 + ac] = acc + bh0s[ac];
          } else if (slot < 32) {      // hw0 = nh0(k)@Wth0
            int s2 = slot - 16; int b = s2 & 3, ac = s2 >> 2;
            float acc = dot_bf(nh0_s[b], Wth0c[ac]);
            hw0_g[b * kA + c0 + ac] = acc + bth0s[ac];
          } else {                     // tapeWhh0 row k (no bias)
            int s2 = slot - 32; int b = s2 & 3, cc = s2 >> 2;
            float acc = dot_bf(nh0_s[b], Whh0c[cc]);
            tWhh0_s[k][cc][b] = f2bfu(acc);
          }
        }
      } else if (slot < 144) {         // layer1 input projections (always)
        if (slot < 96) {               // xw1 = li1@Wx1
          int s2 = slot - 80; int b = s2 & 3, ac = s2 >> 2;
          float acc = dot_bf(li1_s[b], Wx1c[ac]);
          xw1_g[b * kA + c0 + ac] = acc + bx1s[ac];
        } else {                       // gi1 = li1@Wih1 (kept in LDS)
          int s2 = slot - 96; int b = s2 & 3, cc = s2 >> 2;
          float acc = dot_bf(li1_s[b], Wih1c[cc]);
          gi1_s[b][cc] = acc + bih1s[cc];
        }
      } else if (slot < 224) {         // layer1 recurrent products (skip at k==0)
        if (k > 0) {
          if (slot < 160) {            // tapeWh1 row k-1
            int s2 = slot - 144; int b = s2 & 3, ac = s2 >> 2;
            float acc = dot_bf(nh1_s[b], Wh1c[ac]);
            tWh1_g[(size_t)(b * kT + (k - 1)) * kA + c0 + ac] = acc + bh1s[ac];
          } else if (slot < 176) {     // hw1
            int s2 = slot - 160; int b = s2 & 3, ac = s2 >> 2;
            float acc = dot_bf(nh1_s[b], Wth1c[ac]);
            hw1_g[b * kA + c0 + ac] = acc + bth1s[ac];
          } else {                     // tapeWhh1 row k-1
            int s2 = slot - 176; int b = s2 & 3, cc = s2 >> 2;
            float acc = dot_bf(nh1_s[b], Whh1c[cc]);
            tWhh1_s[k - 1][cc][b] = f2bfu(acc);
          }
        }
      }
    }

    gbar(bar);

    // ================= phase Y: attention scores (j-sliced) =================
    if (k < kT - 1) {   // layer0: scores for t0=k+1 (j <= k)
      for (int idx = tid; idx < kB * kA; idx += NTHR) {
        int b = idx >> 8, a = idx & 255;
        xps_s[b][a] = xw0_all[(size_t)(b * kT + (k + 1)) * kA + a] + hw0_g[b * kA + a];
      }
      if ((k >> 2) == bid) {   // gather my new tapeWh0 row
        for (int idx = tid; idx < kB * kA; idx += NTHR) {
          int b = idx >> 8, a = idx & 255;
          tWh0_s[k & 3][b][a] = f2bfu(tWh0_g[(size_t)(b * kT + k) * kA + a]);
        }
      }
      __syncthreads();
      {
        int slot = tid >> 4, lane = tid & 15;
        int jj = slot >> 2, b = slot & 3;
        int j = c0 + jj;
        if (j <= k) {
          float acc = 0.f;
#pragma unroll 4
          for (int ii = 0; ii < 16; ++ii) {
            int a = lane + ii * 16;
            float av = bfu2f(tWh0_s[jj][b][a]) + xps_s[b][a];
            acc += f_tanh(av) * v0s[a];
          }
          acc += __shfl_xor(acc, 8); acc += __shfl_xor(acc, 4);
          acc += __shfl_xor(acc, 2); acc += __shfl_xor(acc, 1);
          if (lane == 0) s0_g[b * kT + j] = acc + bv0s;
        }
      }
      __syncthreads();
    }
    if (k > 0) {        // layer1: scores for t=k (j <= k-1)
      for (int idx = tid; idx < kB * kA; idx += NTHR) {
        int b = idx >> 8, a = idx & 255;
        xps_s[b][a] = xw1_g[b * kA + a] + hw1_g[b * kA + a];
      }
      if (((k - 1) >> 2) == bid) {
        for (int idx = tid; idx < kB * kA; idx += NTHR) {
          int b = idx >> 8, a = idx & 255;
          tWh1_s[(k - 1) & 3][b][a] = f2bfu(tWh1_g[(size_t)(b * kT + (k - 1)) * kA + a]);
        }
      }
      __syncthreads();
      {
        int slot = tid >> 4, lane = tid & 15;
        int jj = slot >> 2, b = slot & 3;
        int j = c0 + jj;
        if (j <= k - 1) {
          float acc = 0.f;
#pragma unroll 4
          for (int ii = 0; ii < 16; ++ii) {
            int a = lane + ii * 16;
            float av = bfu2f(tWh1_s[jj][b][a]) + xps_s[b][a];
            acc += f_tanh(av) * v1s[a];
          }
          acc += __shfl_xor(acc, 8); acc += __shfl_xor(acc, 4);
          acc += __shfl_xor(acc, 2); acc += __shfl_xor(acc, 1);
          if (lane == 0) s1_g[b * kT + j] = acc + bv1s;
        }
      }
    }

    gbar(bar);

    // ================= phase Z: softmax + fused agg/gh + GRU update =========
    if (k < kT - 1) {   // layer0 -> nh0(k+1)
      int t0 = k + 1;
      for (int idx = tid; idx < kB * t0; idx += NTHR) {
        int b = idx / t0, j = idx - b * t0;
        s_s[b][j] = s0_g[b * kT + j];
      }
      __syncthreads();
      {
        int b = tid >> 6, lane = tid & 63;
        float m = -3.0e38f;
        for (int j = lane; j < t0; j += 64) m = fmaxf(m, s_s[b][j]);
        for (int mk = 32; mk >= 1; mk >>= 1) m = fmaxf(m, __shfl_xor(m, mk));
        float sum = 0.f;
        for (int j = lane; j < t0; j += 64) { float e = f_exp(s_s[b][j] - m); s_s[b][j] = e; sum += e; }
        for (int mk = 32; mk >= 1; mk >>= 1) sum += __shfl_xor(sum, mk);
        float inv = frcp(sum);
        for (int j = lane; j < t0; j += 64) s_s[b][j] *= inv;
      }
      __syncthreads();
      {
        int t_id = tid >> 2, sub = tid & 3;
        if (t_id < 48) {               // gh0 = sum_j w_j * tapeWhh0[j] + bhh0
          int cc = t_id >> 2, b = t_id & 3;
          float acc = 0.f;
          for (int j = sub; j < t0; j += 4) acc += s_s[b][j] * bfu2f(tWhh0_s[j][cc][b]);
          acc += __shfl_xor(acc, 1); acc += __shfl_xor(acc, 2);
          if (sub == 0) gh_s[b][cc] = acc + bhh0s[cc];
        } else {                       // agg0 slice
          int s2 = t_id - 48; int c = s2 >> 2, b = s2 & 3;
          float acc = 0.f;
          for (int j = sub; j < t0; j += 4) acc += s_s[b][j] * tape0_s[j][c * 4 + b];
          acc += __shfl_xor(acc, 1); acc += __shfl_xor(acc, 2);
          if (sub == 0) agg_s[b][c] = acc;
        }
      }
      __syncthreads();
      if (tid < 16) {
        int b = tid & 3, c = tid >> 2, hcol = c0 + c;
        const float* gi = gi0_all + (size_t)(b * kT + t0) * 768;
        float agg = agg_s[b][c];
        float r = f_sig(gi[hcol] + gh_s[b][c]);
        float u = f_sig(gi[256 + hcol] + gh_s[b][4 + c]);
        float n = f_tanh(gi[512 + hcol] + r * gh_s[b][8 + c]);
        float val = (1.f - u) * n + u * agg;
        nh0_all[(size_t)(b * kT + t0) * kH + hcol] = val;
        tape0_s[t0][c * 4 + b] = val;
        if (t0 == kT - 1) out_tail[b * kH + hcol] = val;   // h0 final
      }
      __syncthreads();
    }
    {                   // layer1 -> nh1(k)
      if (k > 0) {
        for (int idx = tid; idx < kB * k; idx += NTHR) {
          int b = idx / k, j = idx - b * k;
          s_s[b][j] = s1_g[b * kT + j];
        }
        __syncthreads();
        {
          int b = tid >> 6, lane = tid & 63;
          float m = -3.0e38f;
          for (int j = lane; j < k; j += 64) m = fmaxf(m, s_s[b][j]);
          for (int mk = 32; mk >= 1; mk >>= 1) m = fmaxf(m, __shfl_xor(m, mk));
          float sum = 0.f;
          for (int j = lane; j < k; j += 64) { float e = f_exp(s_s[b][j] - m); s_s[b][j] = e; sum += e; }
          for (int mk = 32; mk >= 1; mk >>= 1) sum += __shfl_xor(sum, mk);
          float inv = frcp(sum);
          for (int j = lane; j < k; j += 64) s_s[b][j] *= inv;
        }
        __syncthreads();
        {
          int t_id = tid >> 2, sub = tid & 3;
          if (t_id < 48) {
            int cc = t_id >> 2, b = t_id & 3;
            float acc = 0.f;
            for (int j = sub; j < k; j += 4) acc += s_s[b][j] * bfu2f(tWhh1_s[j][cc][b]);
            acc += __shfl_xor(acc, 1); acc += __shfl_xor(acc, 2);
            if (sub == 0) gh_s[b][cc] = acc + bhh1s[cc];
          } else {
            int s2 = t_id - 48; int c = s2 >> 2, b = s2 & 3;
            float acc = 0.f;
            for (int j = sub; j < k; j += 4) acc += s_s[b][j] * tape1_s[j][c * 4 + b];
            acc += __shfl_xor(acc, 1); acc += __shfl_xor(acc, 2);
            if (sub == 0) agg_s[b][c] = acc;
          }
        }
        __syncthreads();
      }
      if (tid < 16) {
        int b = tid & 3, c = tid >> 2, hcol = c0 + c;
        float ghr, ghu, ghn, agg;
        if (k > 0) { ghr = gh_s[b][c]; ghu = gh_s[b][4 + c]; ghn = gh_s[b][8 + c]; agg = agg_s[b][c]; }
        else       { ghr = bhh1s[c];  ghu = bhh1s[4 + c];  ghn = bhh1s[8 + c];  agg = 0.f; }
        float r = f_sig(gi1_s[b][c] + ghr);
        float u = f_sig(gi1_s[b][4 + c] + ghu);
        float n = f_tanh(gi1_s[b][8 + c] + r * ghn);
        float val = (1.f - u) * n + u * agg;
        nh1_all[(size_t)(b * kT + k) * kH + hcol] = val;
        tape1_s[k][c * 4 + b] = val;
        cat1_all[(size_t)(b * kT + k) * 512 + hcol] = val;
        if (k == kT - 1) out_tail[kB * kH + b * kH + hcol] = val;   // h1 final
      }
    }
  }
}

// ---------------- launch -----------------------------------------------------
extern "C" void kernel_launch(void* const* d_in, const int* in_sizes, int n_in,
                              void* d_out, int out_size, void* d_ws, size_t ws_size,
                              hipStream_t stream) {
  const int*   input_ids    = (const int*)d_in[0];
  const int*   category_ids = (const int*)d_in[1];
  const float* emb     = (const float*)d_in[2];
  const float* cat_emb = (const float*)d_in[3];
  const float* Wih0 = (const float*)d_in[4];  const float* bih0 = (const float*)d_in[5];
  const float* Whh0 = (const float*)d_in[6];  const float* bhh0 = (const float*)d_in[7];
  const float* Wh0  = (const float*)d_in[8];  const float* bh0  = (const float*)d_in[9];
  const float* Wx0  = (const float*)d_in[10]; const float* bx0  = (const float*)d_in[11];
  const float* Wth0 = (const float*)d_in[12]; const float* bth0 = (const float*)d_in[13];
  const float* v0   = (const float*)d_in[14]; const float* bv0  = (const float*)d_in[15];
  const float* Wih1 = (const float*)d_in[16]; const float* bih1 = (const float*)d_in[17];
  const float* Whh1 = (const float*)d_in[18]; const float* bhh1 = (const float*)d_in[19];
  const float* Wh1  = (const float*)d_in[20]; const float* bh1  = (const float*)d_in[21];
  const float* Wx1  = (const float*)d_in[22]; const float* bx1  = (const float*)d_in[23];
  const float* Wth1 = (const float*)d_in[24]; const float* bth1 = (const float*)d_in[25];
  const float* v1   = (const float*)d_in[26]; const float* bv1  = (const float*)d_in[27];
  const float* Wctx = (const float*)d_in[28]; const float* bctx = (const float*)d_in[29];
  const float* Wout = (const float*)d_in[30]; const float* bout = (const float*)d_in[31];

  float* ws = (float*)d_ws;
  float* li0_all  = ws;                    // [1024][512]
  float* ce_all   = li0_all + 524288;      // [1024][256]
  float* gi0_all  = ce_all + 262144;       // [1024][768]
  float* xw0_all  = gi0_all + 786432;      // [1024][256]
  float* nh0_all  = xw0_all + 262144;      // [B][T][H]
  float* nh1_all  = nh0_all + 262144;
  float* tWh0_g   = nh1_all + 262144;      // [B][T][A]
  float* tWh1_g   = tWh0_g + 262144;
  float* hw0_g    = tWh1_g + 262144;       // [B][A]
  float* hw1_g    = hw0_g + 1024;
  float* xw1_g    = hw1_g + 1024;
  float* s0_g     = xw1_g + 1024;          // [B][T]
  float* s1_g     = s0_g + 1024;
  float* cat1_all = s1_g + 1024;           // [1024][512]
  float* ctx_all  = cat1_all + 524288;     // [1024][500]
  int*   bar      = (int*)(ctx_all + 512000);

  float* out = (float*)d_out;
  float* out_tail = out + (size_t)kB * kT * kV;

  init_kernel<<<dim3(1), dim3(64), 0, stream>>>(bar);
  embed_kernel<<<dim3(kB * kT), dim3(256), 0, stream>>>(input_ids, category_ids, emb, cat_emb,
                                                        li0_all, ce_all, cat1_all);
  gemm_f32<0><<<dim3(12, 16), dim3(256), 0, stream>>>(li0_all, Wih0, bih0, gi0_all, 1024, 768, 512);
  gemm_f32<0><<<dim3(4, 16), dim3(256), 0, stream>>>(li0_all, Wx0, bx0, xw0_all, 1024, 256, 512);
  coop_kernel<<<dim3(NBLK), dim3(NTHR), 0, stream>>>(gi0_all, xw0_all, ce_all, nh0_all, nh1_all,
      tWh0_g, tWh1_g, hw0_g, hw1_g, xw1_g, s0_g, s1_g, cat1_all, out_tail, bar,
      Whh0, bhh0, Wh0, bh0, Wth0, bth0, v0, bv0,
      Wih1, bih1, Whh1, bhh1, Wh1, bh1, Wx1, bx1, Wth1, bth1, v1, bv1);
  gemm_f32<1><<<dim3(8, 16), dim3(256), 0, stream>>>(cat1_all, Wctx, bctx, ctx_all, 1024, 500, 512);
  gemm_f32<0><<<dim3(500, 16), dim3(256), 0, stream>>>(ctx_all, Wout, bout, out, 1024, 32000, 500);
}

// Round 2
// 6714.915 us; speedup vs baseline: 1.4403x; 1.4403x over previous
//
#include <hip/hip_runtime.h>

#define DEVINL __device__ __forceinline__

// Problem constants
constexpr int kB = 4, kT = 256, kH = 256, kA = 256, kV = 32000;
constexpr int NBLK = 64;   // persistent blocks (1 per CU)
constexpr int NTHR = 512;  // 8 waves per block
constexpr int WSL = 4;     // column-slice width = 256 / NBLK

// ---------------- fast math helpers -----------------------------------------
DEVINL float fexp2(float x) { float y; asm("v_exp_f32 %0, %1" : "=v"(y) : "v"(x)); return y; }
DEVINL float frcp(float x)  { float y; asm("v_rcp_f32 %0, %1" : "=v"(y) : "v"(x)); return y; }
DEVINL float f_tanh(float x) {
  float t = fexp2(x * 2.88539008f);           // e^{2x}
  return 1.f - 2.f * frcp(t + 1.f);
}
DEVINL float f_sig(float x) { return frcp(1.f + fexp2(-x * 1.44269504f)); }

DEVINL float bfu2f(unsigned short u) {
  union { unsigned int i; float f; } c; c.i = ((unsigned int)u) << 16; return c.f;
}
DEVINL unsigned short f2bfu(float f) {
  union { float f; unsigned int i; } c; c.f = f;
  unsigned int r = c.i + 0x7fffu + ((c.i >> 16) & 1u);   // RNE
  return (unsigned short)(r >> 16);
}

// dot of f32 LDS vector (len 256) with bf16 LDS weight row (len 256)
DEVINL float dot_bf(const float* x, const unsigned short* w) {
  float acc = 0.f;
  const float4*  x4 = (const float4*)x;
  const ushort4* w4 = (const ushort4*)w;
#pragma unroll 8
  for (int i = 0; i < 64; ++i) {
    float4 xv = x4[i]; ushort4 wv = w4[i];
    acc += xv.x * bfu2f(wv.x);
    acc += xv.y * bfu2f(wv.y);
    acc += xv.z * bfu2f(wv.z);
    acc += xv.w * bfu2f(wv.w);
  }
  return acc;
}

// ---------------- grid barrier: per-block flag lines, monotonic gen ----------
DEVINL void gbar(int* flags, int g) {
  __syncthreads();   // drains every wave's vmem ops (stores + atomics issued)
  int tid = threadIdx.x;
  if (tid == 0)
    __hip_atomic_store(&flags[blockIdx.x * 32], g, __ATOMIC_RELEASE, __HIP_MEMORY_SCOPE_AGENT);
  if (tid < NBLK) {
    int it = 0;
    while (__hip_atomic_load(&flags[tid * 32], __ATOMIC_RELAXED, __HIP_MEMORY_SCOPE_AGENT) < g) {
      __builtin_amdgcn_s_sleep(1);
      if (++it > (1 << 26)) break;   // fail loud, not hang
    }
  }
  __syncthreads();
  __builtin_amdgcn_fence(__ATOMIC_ACQUIRE, "agent");
}

// ---------------- small kernels ----------------------------------------------
__global__ void init_kernel(int* zeros, int nz) {
  for (int i = blockIdx.x * blockDim.x + threadIdx.x; i < nz; i += gridDim.x * blockDim.x)
    zeros[i] = 0;
}

__global__ void embed_kernel(const int* __restrict__ ids, const int* __restrict__ cids,
                             const float* __restrict__ emb, const float* __restrict__ cat_emb,
                             float* __restrict__ li0_all, float* __restrict__ ce_all,
                             float* __restrict__ cat1_all) {
  int bt = blockIdx.x, e = threadIdx.x;
  int id = ids[bt], cid = cids[bt];
  float we = emb[id * kH + e];
  float ce = cat_emb[cid * kH + e];
  li0_all[bt * 512 + e]       = fmaxf(we + ce, 0.f);
  li0_all[bt * 512 + 256 + e] = fmaxf(ce + ce, 0.f);
  ce_all[bt * 256 + e] = ce;
  cat1_all[bt * 512 + 256 + e] = ce;   // upper half of [nh1, ce] concat
}

// ---------------- generic f32 GEMM: C = act(A[M,K] @ W[K,N] + bias) ----------
template <int ACT>
__global__ __launch_bounds__(256) void gemm_f32(const float* __restrict__ A,
                                                const float* __restrict__ Wm,
                                                const float* __restrict__ bias,
                                                float* __restrict__ C,
                                                int M, int N, int K) {
  __shared__ __align__(16) float As[16][68];
  __shared__ __align__(16) float Bs[16][68];
  int tid = threadIdx.x;
  int tx = tid & 15, ty = tid >> 4;
  int row0 = blockIdx.y * 64, col0 = blockIdx.x * 64;
  int ar = tid >> 2;
  int ak = (tid & 3) * 4;
  int br = tid >> 4;
  int bc = (tid & 15) * 4;
  float acc[4][4] = {};
  for (int k0 = 0; k0 < K; k0 += 16) {
    float4 av = {0.f, 0.f, 0.f, 0.f};
    if (k0 + ak < K) av = *(const float4*)(A + (size_t)(row0 + ar) * K + k0 + ak);
    As[ak + 0][ar] = av.x; As[ak + 1][ar] = av.y; As[ak + 2][ar] = av.z; As[ak + 3][ar] = av.w;
    float4 bv = {0.f, 0.f, 0.f, 0.f};
    int wrow = k0 + br;
    if (wrow < K) {
      if (col0 + bc + 3 < N) bv = *(const float4*)(Wm + (size_t)wrow * N + col0 + bc);
      else {
        float t[4] = {0.f, 0.f, 0.f, 0.f};
        for (int u = 0; u < 4; ++u) if (col0 + bc + u < N) t[u] = Wm[(size_t)wrow * N + col0 + bc + u];
        bv.x = t[0]; bv.y = t[1]; bv.z = t[2]; bv.w = t[3];
      }
    }
    *(float4*)&Bs[br][bc] = bv;
    __syncthreads();
#pragma unroll
    for (int kk = 0; kk < 16; ++kk) {
      float4 a4 = *(const float4*)&As[kk][ty * 4];
      float4 b4 = *(const float4*)&Bs[kk][tx * 4];
      acc[0][0] += a4.x * b4.x; acc[0][1] += a4.x * b4.y; acc[0][2] += a4.x * b4.z; acc[0][3] += a4.x * b4.w;
      acc[1][0] += a4.y * b4.x; acc[1][1] += a4.y * b4.y; acc[1][2] += a4.y * b4.z; acc[1][3] += a4.y * b4.w;
      acc[2][0] += a4.z * b4.x; acc[2][1] += a4.z * b4.y; acc[2][2] += a4.z * b4.z; acc[2][3] += a4.z * b4.w;
      acc[3][0] += a4.w * b4.x; acc[3][1] += a4.w * b4.y; acc[3][2] += a4.w * b4.z; acc[3][3] += a4.w * b4.w;
    }
    __syncthreads();
  }
#pragma unroll
  for (int i = 0; i < 4; ++i) {
    int r = row0 + ty * 4 + i;
#pragma unroll
    for (int j = 0; j < 4; ++j) {
      int c = col0 + tx * 4 + j;
      if (c < N) {
        float v = acc[i][j] + bias[c];
        if (ACT == 1) v = f_tanh(v);
        C[(size_t)r * N + c] = v;
      }
    }
  }
}

// ---------------- persistent cooperative recurrence kernel -------------------
// 64 blocks x 512 threads. Block owns a-cols/h-cols [4*bid, 4*bid+4) and the
// matching 12 gate columns. 2 grid barriers per super-step.
// Phase A: local GEMVs (nh@W slices) + partial attention scores over own
//          4 a-cols for ALL j, reduced via int atomicAdd (fixed point 2^20).
// Phase B: softmax (redundant per block) + fused agg/gh + GRU update (own cols).
__global__ __launch_bounds__(NTHR, 1) void coop_kernel(
    const float* __restrict__ gi0_all, const float* __restrict__ xw0_all,
    const float* __restrict__ ce_all,
    float* __restrict__ nh0_all, float* __restrict__ nh1_all,
    float* __restrict__ cat1_all, float* __restrict__ out_tail,
    int* __restrict__ s0buf, int* __restrict__ s1buf, int* __restrict__ flags,
    const float* __restrict__ Whh0, const float* __restrict__ bhh0,
    const float* __restrict__ Wh0, const float* __restrict__ bh0,
    const float* __restrict__ Wth0, const float* __restrict__ bth0,
    const float* __restrict__ v0,
    const float* __restrict__ Wih1, const float* __restrict__ bih1,
    const float* __restrict__ Whh1, const float* __restrict__ bhh1,
    const float* __restrict__ Wh1, const float* __restrict__ bh1,
    const float* __restrict__ Wx1, const float* __restrict__ bx1,
    const float* __restrict__ Wth1, const float* __restrict__ bth1,
    const float* __restrict__ v1) {
  // ---- persistent LDS (~148 KB) ----
  __shared__ __align__(16) unsigned short tWhh0_s[kT][12][4];   // nh@Whh history (bf16)
  __shared__ __align__(16) unsigned short tWhh1_s[kT][12][4];
  __shared__ __align__(16) float tape0_s[kT][16];               // nh history, own 4 h-cols [j][c*4+b]
  __shared__ __align__(16) float tape1_s[kT][16];
  __shared__ __align__(16) unsigned short tWh0_s[4][kT][4];     // tape@Wh own 4 a-cols [b][j][c] bf16
  __shared__ __align__(16) unsigned short tWh1_s[4][kT][4];
  // weight column-slices (bf16, padded rows)
  __shared__ __align__(16) unsigned short Wh0c[WSL][272], Wth0c[WSL][272];
  __shared__ __align__(16) unsigned short Wh1c[WSL][272], Wth1c[WSL][272], Wx1c[WSL][272];
  __shared__ __align__(16) unsigned short Whh0c[12][272], Whh1c[12][272], Wih1c[12][272];
  __shared__ float bh0s[4], bth0s[4], bh1s[4], bth1s[4], bx1s[4];
  __shared__ float bhh0s[12], bhh1s[12], bih1s[12];
  // per-step scratch
  __shared__ __align__(16) float nh0_s[4][260], nh1_s[4][260], li1_s[4][260];
  __shared__ __align__(16) float sm_s[8][260];                  // exp(score) rows: L0 b=0..3, L1 b=0..3
  __shared__ __align__(16) float xps0_s[4][4], xps1a_s[4][4], xps1b_s[4][4];
  __shared__ float gi1_s[4][12], gh0_s[4][12], gh1_s[4][12];
  __shared__ float agg0_s[4][4], agg1_s[4][4], inv_s[8];

  const int bid = blockIdx.x, tid = threadIdx.x;
  const int c0 = bid * WSL;

  // ---- load weight slices (one-time) ----
  for (int idx = tid; idx < WSL * kH; idx += NTHR) {
    int c = idx >> 8, h = idx & 255, col = c0 + c;
    Wh0c[c][h]  = f2bfu(Wh0[h * kA + col]);
    Wth0c[c][h] = f2bfu(Wth0[h * kA + col]);
    Wh1c[c][h]  = f2bfu(Wh1[h * kA + col]);
    Wth1c[c][h] = f2bfu(Wth1[h * kA + col]);
    Wx1c[c][h]  = f2bfu(Wx1[h * kA + col]);
  }
  for (int idx = tid; idx < 12 * kH; idx += NTHR) {
    int cc = idx >> 8, h = idx & 255;
    int n = (cc >> 2) * kH + c0 + (cc & 3);
    Whh0c[cc][h] = f2bfu(Whh0[h * 768 + n]);
    Whh1c[cc][h] = f2bfu(Whh1[h * 768 + n]);
    Wih1c[cc][h] = f2bfu(Wih1[h * 768 + n]);
  }
  if (tid < 4) {
    int c = c0 + tid;
    bh0s[tid] = bh0[c]; bth0s[tid] = bth0[c];
    bh1s[tid] = bh1[c]; bth1s[tid] = bth1[c]; bx1s[tid] = bx1[c];
  }
  if (tid < 12) {
    int n = (tid >> 2) * kH + c0 + (tid & 3);
    bhh0s[tid] = bhh0[n]; bhh1s[tid] = bhh1[n]; bih1s[tid] = bih1[n];
  }
  float4 v0r, v1r;
  v0r.x = v0[c0]; v0r.y = v0[c0+1]; v0r.z = v0[c0+2]; v0r.w = v0[c0+3];
  v1r.x = v1[c0]; v1r.y = v1[c0+1]; v1r.z = v1[c0+2]; v1r.w = v1[c0+3];
  __syncthreads();

  // ---- prologue: nh0(0) (t=0: agg=h=0, gh=bhh) ----
  if (tid < 16) {
    int b = tid & 3, c = tid >> 2, hcol = c0 + c;
    const float* gi = gi0_all + (size_t)(b * kT) * 768;
    float r = f_sig(gi[hcol] + bhh0s[c]);
    float u = f_sig(gi[256 + hcol] + bhh0s[4 + c]);
    float n = f_tanh(gi[512 + hcol] + r * bhh0s[8 + c]);
    float val = (1.f - u) * n;
    nh0_all[(size_t)(b * kT) * kH + hcol] = val;
    tape0_s[0][c * 4 + b] = val;
  }

  int g = 0;
  const float fx = 1048576.f;               // fixed-point scale 2^20
  const float fxi = 1.44269504f / 1048576.f; // log2(e)/2^20

  for (int k = 0; k < kT; ++k) {
    gbar(flags, ++g);   // publishes nh0(k), nh1(k-1), prior zeroings

    // ================= phase A =================
    for (int idx = tid; idx < kB * kH; idx += NTHR) {
      int b = idx >> 8, h = idx & 255;
      float n0v = nh0_all[(size_t)(b * kT + k) * kH + h];
      nh0_s[b][h] = n0v;
      float cev = ce_all[(size_t)(b * kT + k) * kH + h];
      li1_s[b][h] = fmaxf(n0v + cev, 0.f);
      if (k > 0) nh1_s[b][h] = nh1_all[(size_t)(b * kT + k - 1) * kH + h];
    }
    // zero the score buffers consumed last step (own j-slice); disjoint parity
    // from this step's atomicAdd targets, barrier-separated from readers.
    if (tid >= NTHR - 32) {
      int z = tid - (NTHR - 32);
      int which = z >> 4, r2 = z & 15, b = r2 & 3, jj = r2 >> 2;
      int j = bid * 4 + jj;
      if (which == 0) s0buf[(k & 1) * 1024 + b * 256 + j] = 0;
      else            s1buf[((k + 1) & 1) * 1024 + b * 256 + j] = 0;
    }
    __syncthreads();

    {   // 224 local GEMVs, one per thread
      int slot = tid;
      if (slot < 80) {
        if (k < kT - 1) {
          if (slot < 16) {            // hw0 (+bth) + xw0 -> xps0
            int b = slot & 3, c = slot >> 2;
            float acc = dot_bf(nh0_s[b], Wth0c[c]);
            float xw = xw0_all[(size_t)(b * kT + k + 1) * kA + c0 + c];
            xps0_s[b][c] = acc + bth0s[c] + xw;
          } else if (slot < 32) {     // tape@Wh0 row k (own cols, +bh)
            int s2 = slot - 16; int b = s2 & 3, c = s2 >> 2;
            float acc = dot_bf(nh0_s[b], Wh0c[c]);
            tWh0_s[b][k][c] = f2bfu(acc + bh0s[c]);
          } else {                    // tape@Whh0 row k
            int s2 = slot - 32; int b = s2 & 3, cc = s2 >> 2;
            float acc = dot_bf(nh0_s[b], Whh0c[cc]);
            tWhh0_s[k][cc][b] = f2bfu(acc);
          }
        }
      } else if (slot < 144) {
        if (slot < 96) {              // xw1 = li1@Wx1 (+bx)
          int s2 = slot - 80; int b = s2 & 3, c = s2 >> 2;
          float acc = dot_bf(li1_s[b], Wx1c[c]);
          xps1a_s[b][c] = acc + bx1s[c];
        } else {                      // gi1 = li1@Wih1 (+bih)
          int s3 = slot - 96; int b = s3 & 3, cc = s3 >> 2;
          float acc = dot_bf(li1_s[b], Wih1c[cc]);
          gi1_s[b][cc] = acc + bih1s[cc];
        }
      } else if (slot < 224) {
        if (k > 0) {
          if (slot < 160) {           // hw1 (+bth)
            int s2 = slot - 144; int b = s2 & 3, c = s2 >> 2;
            float acc = dot_bf(nh1_s[b], Wth1c[c]);
            xps1b_s[b][c] = acc + bth1s[c];
          } else if (slot < 176) {    // tape@Wh1 row k-1 (+bh)
            int s3 = slot - 160; int b = s3 & 3, c = s3 >> 2;
            float acc = dot_bf(nh1_s[b], Wh1c[c]);
            tWh1_s[b][k - 1][c] = f2bfu(acc + bh1s[c]);
          } else {                    // tape@Whh1 row k-1
            int s3 = slot - 176; int b = s3 & 3, cc = s3 >> 2;
            float acc = dot_bf(nh1_s[b], Whh1c[cc]);
            tWhh1_s[k - 1][cc][b] = f2bfu(acc);
          }
        }
      }
    }
    __syncthreads();

    {   // partial scores over own 4 a-cols, all j; int atomicAdd reduce
      int ns0 = (k < kT - 1) ? (k + 1) * 4 : 0;
      int ns1 = k * 4;
      int* d0 = s0buf + ((k + 1) & 1) * 1024;
      int* d1 = s1buf + (k & 1) * 1024;
      for (int s = tid; s < ns0 + ns1; s += NTHR) {
        float part; int* dst;
        if (s < ns0) {
          int j = s >> 2, b = s & 3;
          ushort4 p4 = *(const ushort4*)&tWh0_s[b][j][0];
          float4 xp = *(const float4*)&xps0_s[b][0];
          part  = f_tanh(bfu2f(p4.x) + xp.x) * v0r.x;
          part += f_tanh(bfu2f(p4.y) + xp.y) * v0r.y;
          part += f_tanh(bfu2f(p4.z) + xp.z) * v0r.z;
          part += f_tanh(bfu2f(p4.w) + xp.w) * v0r.w;
          dst = d0 + b * 256 + j;
        } else {
          int ss = s - ns0; int j = ss >> 2, b = ss & 3;
          ushort4 p4 = *(const ushort4*)&tWh1_s[b][j][0];
          float4 xa = *(const float4*)&xps1a_s[b][0];
          float4 xb = *(const float4*)&xps1b_s[b][0];
          part  = f_tanh(bfu2f(p4.x) + xa.x + xb.x) * v1r.x;
          part += f_tanh(bfu2f(p4.y) + xa.y + xb.y) * v1r.y;
          part += f_tanh(bfu2f(p4.z) + xa.z + xb.z) * v1r.z;
          part += f_tanh(bfu2f(p4.w) + xa.w + xb.w) * v1r.w;
          dst = d1 + b * 256 + j;
        }
        int q = (int)rintf(part * fx);
        __hip_atomic_fetch_add(dst, q, __ATOMIC_RELAXED, __HIP_MEMORY_SCOPE_AGENT);
      }
    }

    gbar(flags, ++g);   // publishes score sums

    // ================= phase B =================
    int cnt0 = (k < kT - 1) ? (k + 1) : 0;
    int cnt1 = k;
    {   // exp(score) rows + sum (softmax shift-invariant: no max, no bv)
      int r = tid >> 6, lane = tid & 63;
      float sum = 0.f;
      if (r < 4) {
        if (cnt0) {
          const int* sb = s0buf + ((k + 1) & 1) * 1024 + r * 256;
          for (int j = lane; j < cnt0; j += 64) {
            float e = fexp2((float)sb[j] * fxi);
            sm_s[r][j] = e; sum += e;
          }
        }
      } else {
        if (cnt1) {
          const int* sb = s1buf + (k & 1) * 1024 + (r - 4) * 256;
          for (int j = lane; j < cnt1; j += 64) {
            float e = fexp2((float)sb[j] * fxi);
            sm_s[r][j] = e; sum += e;
          }
        }
      }
      for (int m = 32; m >= 1; m >>= 1) sum += __shfl_xor(sum, m);
      if (lane == 0) inv_s[r] = frcp(sum);
    }
    __syncthreads();

    {   // fused gh (=sum w*tapeWhh) and agg (=sum w*tape), own cols
      int slot = tid >> 2, sub = tid & 3;
      float acc = 0.f;
      if (slot < 48) {
        if (cnt0) {
          int b = slot & 3, cc = slot >> 2;
          for (int j = sub; j < cnt0; j += 4) acc += sm_s[b][j] * bfu2f(tWhh0_s[j][cc][b]);
          acc += __shfl_xor(acc, 1); acc += __shfl_xor(acc, 2);
          if (sub == 0) gh0_s[b][cc] = acc * inv_s[b] + bhh0s[cc];
        }
      } else if (slot < 64) {
        if (cnt0) {
          int s2 = slot - 48; int b = s2 & 3, c = s2 >> 2;
          for (int j = sub; j < cnt0; j += 4) acc += sm_s[b][j] * tape0_s[j][c * 4 + b];
          acc += __shfl_xor(acc, 1); acc += __shfl_xor(acc, 2);
          if (sub == 0) agg0_s[b][c] = acc * inv_s[b];
        }
      } else if (slot < 112) {
        if (cnt1) {
          int s2 = slot - 64; int b = s2 & 3, cc = s2 >> 2;
          for (int j = sub; j < cnt1; j += 4) acc += sm_s[4 + b][j] * bfu2f(tWhh1_s[j][cc][b]);
          acc += __shfl_xor(acc, 1); acc += __shfl_xor(acc, 2);
          if (sub == 0) gh1_s[b][cc] = acc * inv_s[4 + b] + bhh1s[cc];
        }
      } else if (slot < 128) {
        if (cnt1) {
          int s2 = slot - 112; int b = s2 & 3, c = s2 >> 2;
          for (int j = sub; j < cnt1; j += 4) acc += sm_s[4 + b][j] * tape1_s[j][c * 4 + b];
          acc += __shfl_xor(acc, 1); acc += __shfl_xor(acc, 2);
          if (sub == 0) agg1_s[b][c] = acc * inv_s[4 + b];
        }
      }
    }
    __syncthreads();

    // GRU updates (two waves in parallel)
    if (tid < 16) {            // L0 -> nh0(k+1)
      if (k < kT - 1) {
        int b = tid & 3, c = tid >> 2, hcol = c0 + c, t0 = k + 1;
        const float* gi = gi0_all + (size_t)(b * kT + t0) * 768;
        float agg = agg0_s[b][c];
        float r = f_sig(gi[hcol] + gh0_s[b][c]);
        float u = f_sig(gi[256 + hcol] + gh0_s[b][4 + c]);
        float n = f_tanh(gi[512 + hcol] + r * gh0_s[b][8 + c]);
        float val = (1.f - u) * n + u * agg;
        nh0_all[(size_t)(b * kT + t0) * kH + hcol] = val;
        tape0_s[t0][c * 4 + b] = val;
        if (t0 == kT - 1) out_tail[b * kH + hcol] = val;      // h0 final
      }
    } else if (tid >= 64 && tid < 80) {   // L1 -> nh1(k)
      int t2 = tid - 64; int b = t2 & 3, c = t2 >> 2, hcol = c0 + c;
      float ghr, ghu, ghn, agg;
      if (k > 0) { ghr = gh1_s[b][c]; ghu = gh1_s[b][4 + c]; ghn = gh1_s[b][8 + c]; agg = agg1_s[b][c]; }
      else       { ghr = bhh1s[c];    ghu = bhh1s[4 + c];    ghn = bhh1s[8 + c];    agg = 0.f; }
      float r = f_sig(gi1_s[b][c] + ghr);
      float u = f_sig(gi1_s[b][4 + c] + ghu);
      float n = f_tanh(gi1_s[b][8 + c] + r * ghn);
      float val = (1.f - u) * n + u * agg;
      nh1_all[(size_t)(b * kT + k) * kH + hcol] = val;
      tape1_s[k][c * 4 + b] = val;
      cat1_all[(size_t)(b * kT + k) * 512 + hcol] = val;
      if (k == kT - 1) out_tail[kB * kH + b * kH + hcol] = val; // h1 final
    }
  }
}

// ---------------- launch -----------------------------------------------------
extern "C" void kernel_launch(void* const* d_in, const int* in_sizes, int n_in,
                              void* d_out, int out_size, void* d_ws, size_t ws_size,
                              hipStream_t stream) {
  const int*   input_ids    = (const int*)d_in[0];
  const int*   category_ids = (const int*)d_in[1];
  const float* emb     = (const float*)d_in[2];
  const float* cat_emb = (const float*)d_in[3];
  const float* Wih0 = (const float*)d_in[4];  const float* bih0 = (const float*)d_in[5];
  const float* Whh0 = (const float*)d_in[6];  const float* bhh0 = (const float*)d_in[7];
  const float* Wh0  = (const float*)d_in[8];  const float* bh0  = (const float*)d_in[9];
  const float* Wx0  = (const float*)d_in[10]; const float* bx0  = (const float*)d_in[11];
  const float* Wth0 = (const float*)d_in[12]; const float* bth0 = (const float*)d_in[13];
  const float* v0   = (const float*)d_in[14];
  const float* Wih1 = (const float*)d_in[16]; const float* bih1 = (const float*)d_in[17];
  const float* Whh1 = (const float*)d_in[18]; const float* bhh1 = (const float*)d_in[19];
  const float* Wh1  = (const float*)d_in[20]; const float* bh1  = (const float*)d_in[21];
  const float* Wx1  = (const float*)d_in[22]; const float* bx1  = (const float*)d_in[23];
  const float* Wth1 = (const float*)d_in[24]; const float* bth1 = (const float*)d_in[25];
  const float* v1   = (const float*)d_in[26];
  const float* Wctx = (const float*)d_in[28]; const float* bctx = (const float*)d_in[29];
  const float* Wout = (const float*)d_in[30]; const float* bout = (const float*)d_in[31];

  float* ws = (float*)d_ws;
  float* li0_all  = ws;                    // [1024][512]
  float* ce_all   = li0_all + 524288;      // [1024][256]
  float* gi0_all  = ce_all + 262144;       // [1024][768]
  float* xw0_all  = gi0_all + 786432;      // [1024][256]
  float* nh0_all  = xw0_all + 262144;      // [B*T][H]
  float* nh1_all  = nh0_all + 262144;
  float* cat1_all = nh1_all + 262144;      // [1024][512]
  float* ctx_all  = cat1_all + 524288;     // [1024][500]
  int*   s0buf    = (int*)(ctx_all + 512000);  // [2][4][256]
  int*   s1buf    = s0buf + 2048;              // [2][4][256]
  int*   flags    = s1buf + 2048;              // [64][32]

  float* out = (float*)d_out;
  float* out_tail = out + (size_t)kB * kT * kV;

  init_kernel<<<dim3(8), dim3(512), 0, stream>>>(s0buf, 2048 + 2048 + NBLK * 32);
  embed_kernel<<<dim3(kB * kT), dim3(256), 0, stream>>>(input_ids, category_ids, emb, cat_emb,
                                                        li0_all, ce_all, cat1_all);
  gemm_f32<0><<<dim3(12, 16), dim3(256), 0, stream>>>(li0_all, Wih0, bih0, gi0_all, 1024, 768, 512);
  gemm_f32<0><<<dim3(4, 16), dim3(256), 0, stream>>>(li0_all, Wx0, bx0, xw0_all, 1024, 256, 512);
  coop_kernel<<<dim3(NBLK), dim3(NTHR), 0, stream>>>(gi0_all, xw0_all, ce_all, nh0_all, nh1_all,
      cat1_all, out_tail, s0buf, s1buf, flags,
      Whh0, bhh0, Wh0, bh0, Wth0, bth0, v0,
      Wih1, bih1, Whh1, bhh1, Wh1, bh1, Wx1, bx1, Wth1, bth1, v1);
  gemm_f32<1><<<dim3(8, 16), dim3(256), 0, stream>>>(cat1_all, Wctx, bctx, ctx_all, 1024, 500, 512);
  gemm_f32<0><<<dim3(500, 16), dim3(256), 0, stream>>>(ctx_all, Wout, bout, out, 1024, 32000, 500);
}